// Round 1
// baseline (544.404 us; speedup 1.0000x reference)
//
#include <hip/hip_runtime.h>

// Problem constants (from reference): T=64, N=20000, F=8, H=32, E=320000 (unused).
#define T_STEPS 64
#define N_NODES 20000
#define F_IN    8
#define H_DIM   32
#define NODES_PER_BLOCK 8
#define BLOCK   (NODES_PER_BLOCK * H_DIM)   // 256 threads, 4 waves
#define NEG_SLOPE 0.01f

__device__ __forceinline__ float sigmoid_f(float x) {
    return 1.0f / (1.0f + __expf(-x));
}
__device__ __forceinline__ float tanh_f(float x) {
    // tanh(x) = 1 - 2/(exp(2x)+1); saturates correctly at +/-inf
    return 1.0f - 2.0f / (1.0f + __expf(2.0f * x));
}
__device__ __forceinline__ float leaky_f(float x) {
    return x > 0.0f ? x : NEG_SLOPE * x;
}

__global__ void init_out_kernel(const float* __restrict__ b2, float* __restrict__ out) {
    int t = threadIdx.x;
    if (t < T_STEPS) out[t] = b2[0];
}

__global__ __launch_bounds__(BLOCK, 2) void rgcn_kernel(
    const float* __restrict__ x,    // [T,N,F]
    const float* __restrict__ h0,   // [N,H]
    const float* __restrict__ Wxz, const float* __restrict__ bxz,
    const float* __restrict__ Whz, const float* __restrict__ bhz,
    const float* __restrict__ Wxr, const float* __restrict__ bxr,
    const float* __restrict__ Whr, const float* __restrict__ bhr,
    const float* __restrict__ Wxh, const float* __restrict__ bxh,
    const float* __restrict__ Whh, const float* __restrict__ bhh,
    const float* __restrict__ W1,  const float* __restrict__ b1,
    const float* __restrict__ W2,
    float* __restrict__ out)        // [T] then [N,H]
{
    const int tid  = threadIdx.x;
    const int j    = tid & (H_DIM - 1);   // channel
    const int nl   = tid >> 5;            // node-local 0..7
    const int node = blockIdx.x * NODES_PER_BLOCK + nl;

    __shared__ __align__(16) float hbuf [NODES_PER_BLOCK][H_DIM];
    __shared__ __align__(16) float rhbuf[NODES_PER_BLOCK][H_DIM];
    __shared__ __align__(16) float xbuf [NODES_PER_BLOCK * F_IN];
    __shared__ float outacc[T_STEPS];

    // ---- per-thread weight columns in VGPRs ----
    float wxz[F_IN], wxr[F_IN], wxh[F_IN];
#pragma unroll
    for (int f = 0; f < F_IN; ++f) {
        wxz[f] = Wxz[f * H_DIM + j];
        wxr[f] = Wxr[f * H_DIM + j];
        wxh[f] = Wxh[f * H_DIM + j];
    }
    float whz[H_DIM], whr[H_DIM], whh[H_DIM];
#pragma unroll
    for (int k = 0; k < H_DIM; ++k) {
        whz[k] = Whz[k * H_DIM + j];
        whr[k] = Whr[k * H_DIM + j];
        whh[k] = Whh[k * H_DIM + j];
    }
    const float bz  = bxz[j] + bhz[j];
    const float br  = bxr[j] + bhr[j];
    const float bh  = bxh[j] + bhh[j];
    const float w1j = W1[j];
    const float b1s = b1[0];
    const float w2n = W2[node];

    float hj = h0[node * H_DIM + j];
    hbuf[nl][j] = hj;
    if (tid < T_STEPS) outacc[tid] = 0.0f;
    __syncthreads();

#pragma unroll 1
    for (int t = 0; t < T_STEPS; ++t) {
        // stage this step's x slice for the block's 8 nodes (64 contiguous floats)
        if (tid < NODES_PER_BLOCK * F_IN)
            xbuf[tid] = x[t * (N_NODES * F_IN) + blockIdx.x * (NODES_PER_BLOCK * F_IN) + tid];
        __syncthreads();

        // x-part of the three gates
        float xz = bz, xr = br, xh = bh;
#pragma unroll
        for (int f = 0; f < F_IN; ++f) {
            float xv = xbuf[nl * F_IN + f];
            xz += xv * wxz[f];
            xr += xv * wxr[f];
            xh += xv * wxh[f];
        }

        // h-part for z and r (read h row as float4 broadcasts)
        float hz = 0.0f, hr = 0.0f;
        const float4* hrow = (const float4*)(&hbuf[nl][0]);
#pragma unroll
        for (int q = 0; q < H_DIM / 4; ++q) {
            float4 hv = hrow[q];
            hz += hv.x * whz[4*q+0]; hr += hv.x * whr[4*q+0];
            hz += hv.y * whz[4*q+1]; hr += hv.y * whr[4*q+1];
            hz += hv.z * whz[4*q+2]; hr += hv.z * whr[4*q+2];
            hz += hv.w * whz[4*q+3]; hr += hv.w * whr[4*q+3];
        }
        float z = sigmoid_f(xz + hz);
        float r = sigmoid_f(xr + hr);

        rhbuf[nl][j] = r * hj;
        __syncthreads();

        // (h*r) @ Whh
        float hh = 0.0f;
        const float4* rrow = (const float4*)(&rhbuf[nl][0]);
#pragma unroll
        for (int q = 0; q < H_DIM / 4; ++q) {
            float4 rv = rrow[q];
            hh += rv.x * whh[4*q+0];
            hh += rv.y * whh[4*q+1];
            hh += rv.z * whh[4*q+2];
            hh += rv.w * whh[4*q+3];
        }
        float ht = tanh_f(xh + hh);
        float hn = z * hj + (1.0f - z) * ht;

        // safe: all phase-1 reads of hbuf finished before 2nd barrier
        hbuf[nl][j] = hn;
        hj = hn;

        // fused head: leaky(hn) @ W1 -> +b1 -> leaky -> * W2[n], reduce over channels
        float p = leaky_f(hn) * w1j;
#pragma unroll
        for (int m = 16; m >= 1; m >>= 1)
            p += __shfl_xor(p, m, 32);
        if (j == 0) {
            float a2 = leaky_f(p + b1s);
            atomicAdd(&outacc[t], a2 * w2n);
        }
    }
    __syncthreads();

    if (tid < T_STEPS) atomicAdd(&out[tid], outacc[tid]);

    // h_fin: out[64 + node*32 + j] == out[64 + blockIdx*256 + tid]
    out[T_STEPS + blockIdx.x * BLOCK + tid] = hj;
}

extern "C" void kernel_launch(void* const* d_in, const int* in_sizes, int n_in,
                              void* d_out, int out_size, void* d_ws, size_t ws_size,
                              hipStream_t stream) {
    const float* x    = (const float*)d_in[0];
    // d_in[1] edge_index (int64), d_in[2] edge_weight: dead for K=1 ChebConv
    const float* h0   = (const float*)d_in[3];
    const float* Wxz  = (const float*)d_in[4];
    const float* bxz  = (const float*)d_in[5];
    const float* Whz  = (const float*)d_in[6];
    const float* bhz  = (const float*)d_in[7];
    const float* Wxr  = (const float*)d_in[8];
    const float* bxr  = (const float*)d_in[9];
    const float* Whr  = (const float*)d_in[10];
    const float* bhr  = (const float*)d_in[11];
    const float* Wxh  = (const float*)d_in[12];
    const float* bxh  = (const float*)d_in[13];
    const float* Whh  = (const float*)d_in[14];
    const float* bhh  = (const float*)d_in[15];
    const float* W1   = (const float*)d_in[16];
    const float* b1   = (const float*)d_in[17];
    const float* W2   = (const float*)d_in[18];
    const float* b2   = (const float*)d_in[19];
    float* out = (float*)d_out;

    init_out_kernel<<<1, 64, 0, stream>>>(b2, out);

    const int grid = N_NODES / NODES_PER_BLOCK;  // 20000/8 = 2500, exact
    rgcn_kernel<<<grid, BLOCK, 0, stream>>>(
        x, h0, Wxz, bxz, Whz, bhz, Wxr, bxr, Whr, bhr,
        Wxh, bxh, Whh, bhh, W1, b1, W2, out);
}

// Round 2
// 497.306 us; speedup vs baseline: 1.0947x; 1.0947x over previous
//
#include <hip/hip_runtime.h>

// T=64, N=20000, F=8, H=32, E=320000 (edge inputs dead for K=1 ChebConv).
#define T_STEPS 64
#define N_NODES 20000
#define F_IN    8
#define H_DIM   32
#define NODES_PER_THREAD 4
#define GROUPS  8                                   // 32-lane groups per block
#define NODES_PER_BLOCK (GROUPS * NODES_PER_THREAD) // 32
#define BLOCK   256
#define NEG_SLOPE 0.01f

__device__ __forceinline__ float sigmoid_f(float x) {
    return 1.0f / (1.0f + __expf(-x));
}
__device__ __forceinline__ float tanh_f(float x) {
    return 1.0f - 2.0f / (1.0f + __expf(2.0f * x));
}
__device__ __forceinline__ float leaky_f(float x) {
    return x > 0.0f ? x : NEG_SLOPE * x;
}

__global__ void init_out_kernel(const float* __restrict__ b2, float* __restrict__ out) {
    int t = threadIdx.x;
    if (t < T_STEPS) out[t] = b2[0];
}

__global__ __launch_bounds__(BLOCK, 2) void rgcn_kernel(
    const float* __restrict__ x,    // [T,N,F]
    const float* __restrict__ h0,   // [N,H]
    const float* __restrict__ Wxz, const float* __restrict__ bxz,
    const float* __restrict__ Whz, const float* __restrict__ bhz,
    const float* __restrict__ Wxr, const float* __restrict__ bxr,
    const float* __restrict__ Whr, const float* __restrict__ bhr,
    const float* __restrict__ Wxh, const float* __restrict__ bxh,
    const float* __restrict__ Whh, const float* __restrict__ bhh,
    const float* __restrict__ W1,  const float* __restrict__ b1,
    const float* __restrict__ W2,
    float* __restrict__ out)        // [T] then [N,H]
{
    const int tid = threadIdx.x;
    const int j   = tid & (H_DIM - 1);  // channel 0..31
    const int g   = tid >> 5;           // lane-group 0..7

    __shared__ __align__(16) float hbuf [NODES_PER_BLOCK][H_DIM]; // 4 KB
    __shared__ __align__(16) float rhbuf[NODES_PER_BLOCK][H_DIM]; // 4 KB
    __shared__ __align__(16) float xbuf [NODES_PER_BLOCK * F_IN]; // 1 KB
    __shared__ float outacc[T_STEPS];

    // ---- per-thread weight columns in VGPRs (shared by 4 nodes) ----
    float wxz[F_IN], wxr[F_IN], wxh[F_IN];
#pragma unroll
    for (int f = 0; f < F_IN; ++f) {
        wxz[f] = Wxz[f * H_DIM + j];
        wxr[f] = Wxr[f * H_DIM + j];
        wxh[f] = Wxh[f * H_DIM + j];
    }
    float whz[H_DIM], whr[H_DIM], whh[H_DIM];
#pragma unroll
    for (int k = 0; k < H_DIM; ++k) {
        whz[k] = Whz[k * H_DIM + j];
        whr[k] = Whr[k * H_DIM + j];
        whh[k] = Whh[k * H_DIM + j];
    }
    const float bz  = bxz[j] + bhz[j];
    const float br  = bxr[j] + bhr[j];
    const float bh  = bxh[j] + bhh[j];
    const float w1j = W1[j];
    const float b1s = b1[0];

    const int nodebase = blockIdx.x * NODES_PER_BLOCK + g * NODES_PER_THREAD;
    const int rowbase  = g * NODES_PER_THREAD;

    float w2[NODES_PER_THREAD];
    float hj[NODES_PER_THREAD];
#pragma unroll
    for (int i = 0; i < NODES_PER_THREAD; ++i) {
        w2[i] = W2[nodebase + i];
        hj[i] = h0[(nodebase + i) * H_DIM + j];
        hbuf[rowbase + i][j] = hj[i];
    }
    if (tid < T_STEPS) outacc[tid] = 0.0f;
    __syncthreads();

#pragma unroll 1
    for (int t = 0; t < T_STEPS; ++t) {
        // stage this step's x slice: 32 nodes x 8 feats = 256 contiguous floats
        xbuf[tid] = x[t * (N_NODES * F_IN) + blockIdx.x * (NODES_PER_BLOCK * F_IN) + tid];
        __syncthreads();  // xbuf ready; hbuf writes from prev step visible

        float xz[NODES_PER_THREAD], xr[NODES_PER_THREAD], xh[NODES_PER_THREAD];
        float z[NODES_PER_THREAD];
#pragma unroll
        for (int i = 0; i < NODES_PER_THREAD; ++i) {
            const float4* xr4 = (const float4*)&xbuf[(rowbase + i) * F_IN];
            float4 x0 = xr4[0], x1 = xr4[1];
            float az = bz, ar = br, ah = bh;
            az += x0.x * wxz[0]; ar += x0.x * wxr[0]; ah += x0.x * wxh[0];
            az += x0.y * wxz[1]; ar += x0.y * wxr[1]; ah += x0.y * wxh[1];
            az += x0.z * wxz[2]; ar += x0.z * wxr[2]; ah += x0.z * wxh[2];
            az += x0.w * wxz[3]; ar += x0.w * wxr[3]; ah += x0.w * wxh[3];
            az += x1.x * wxz[4]; ar += x1.x * wxr[4]; ah += x1.x * wxh[4];
            az += x1.y * wxz[5]; ar += x1.y * wxr[5]; ah += x1.y * wxh[5];
            az += x1.z * wxz[6]; ar += x1.z * wxr[6]; ah += x1.z * wxh[6];
            az += x1.w * wxz[7]; ar += x1.w * wxr[7]; ah += x1.w * wxh[7];
            xz[i] = az; xr[i] = ar; xh[i] = ah;
        }

        // h-part for z and r; write r*h
#pragma unroll
        for (int i = 0; i < NODES_PER_THREAD; ++i) {
            const float4* hrow = (const float4*)&hbuf[rowbase + i][0];
            float hz = 0.0f, hr = 0.0f;
#pragma unroll
            for (int q = 0; q < H_DIM / 4; ++q) {
                float4 hv = hrow[q];
                hz += hv.x * whz[4*q+0]; hr += hv.x * whr[4*q+0];
                hz += hv.y * whz[4*q+1]; hr += hv.y * whr[4*q+1];
                hz += hv.z * whz[4*q+2]; hr += hv.z * whr[4*q+2];
                hz += hv.w * whz[4*q+3]; hr += hv.w * whr[4*q+3];
            }
            z[i] = sigmoid_f(xz[i] + hz);
            float r = sigmoid_f(xr[i] + hr);
            rhbuf[rowbase + i][j] = r * hj[i];
        }
        __syncthreads();  // rhbuf ready

        float p[NODES_PER_THREAD];
#pragma unroll
        for (int i = 0; i < NODES_PER_THREAD; ++i) {
            const float4* rrow = (const float4*)&rhbuf[rowbase + i][0];
            float hh = 0.0f;
#pragma unroll
            for (int q = 0; q < H_DIM / 4; ++q) {
                float4 rv = rrow[q];
                hh += rv.x * whh[4*q+0];
                hh += rv.y * whh[4*q+1];
                hh += rv.z * whh[4*q+2];
                hh += rv.w * whh[4*q+3];
            }
            float ht = tanh_f(xh[i] + hh);
            float hn = z[i] * hj[i] + (1.0f - z[i]) * ht;
            hbuf[rowbase + i][j] = hn;   // readers are past barrier above
            hj[i] = hn;
            p[i] = leaky_f(hn) * w1j;
        }

        // head reduction over channels (width-32 butterflies, 4 independent chains)
#pragma unroll
        for (int m = 16; m >= 1; m >>= 1) {
#pragma unroll
            for (int i = 0; i < NODES_PER_THREAD; ++i)
                p[i] += __shfl_xor(p[i], m, 32);
        }
        if (j == 0) {
            float s = 0.0f;
#pragma unroll
            for (int i = 0; i < NODES_PER_THREAD; ++i)
                s += leaky_f(p[i] + b1s) * w2[i];
            atomicAdd(&outacc[t], s);
        }
    }
    __syncthreads();

    if (tid < T_STEPS) atomicAdd(&out[tid], outacc[tid]);

#pragma unroll
    for (int i = 0; i < NODES_PER_THREAD; ++i)
        out[T_STEPS + (nodebase + i) * H_DIM + j] = hj[i];
}

extern "C" void kernel_launch(void* const* d_in, const int* in_sizes, int n_in,
                              void* d_out, int out_size, void* d_ws, size_t ws_size,
                              hipStream_t stream) {
    const float* x    = (const float*)d_in[0];
    // d_in[1] edge_index (int64), d_in[2] edge_weight: dead for K=1 ChebConv
    const float* h0   = (const float*)d_in[3];
    const float* Wxz  = (const float*)d_in[4];
    const float* bxz  = (const float*)d_in[5];
    const float* Whz  = (const float*)d_in[6];
    const float* bhz  = (const float*)d_in[7];
    const float* Wxr  = (const float*)d_in[8];
    const float* bxr  = (const float*)d_in[9];
    const float* Whr  = (const float*)d_in[10];
    const float* bhr  = (const float*)d_in[11];
    const float* Wxh  = (const float*)d_in[12];
    const float* bxh  = (const float*)d_in[13];
    const float* Whh  = (const float*)d_in[14];
    const float* bhh  = (const float*)d_in[15];
    const float* W1   = (const float*)d_in[16];
    const float* b1   = (const float*)d_in[17];
    const float* W2   = (const float*)d_in[18];
    const float* b2   = (const float*)d_in[19];
    float* out = (float*)d_out;

    init_out_kernel<<<1, 64, 0, stream>>>(b2, out);

    const int grid = N_NODES / NODES_PER_BLOCK;  // 20000/32 = 625, exact
    rgcn_kernel<<<grid, BLOCK, 0, stream>>>(
        x, h0, Wxz, bxz, Whz, bhz, Wxr, bxr, Whr, bhr,
        Wxh, bxh, Whh, bhh, W1, b1, W2, out);
}